// Round 12
// baseline (325.617 us; speedup 1.0000x reference)
//
#include <hip/hip_runtime.h>
#include <hip/hip_bf16.h>
#include <math.h>

#define EPS 1e-5f
#define BB 4
#define CHIGH 256
#define CLOW 128
#define NN 4096
#define NHEADS 4
#define HDIM 32
#define FFN_DIM 256
#define SPLITS 4

typedef __bf16 b8 __attribute__((ext_vector_type(8)));
typedef float f4 __attribute__((ext_vector_type(4)));

__device__ __forceinline__ unsigned int cvt_pk(float lo, float hi) {
    float2 t; t.x = lo; t.y = hi;
    __hip_bfloat162 h = __float22bfloat162_rn(t);
    unsigned int r;
    __builtin_memcpy(&r, &h, sizeof(r));
    return r;
}
__device__ __forceinline__ float b2f(unsigned short u) {
    unsigned int x = ((unsigned int)u) << 16;
    float f;
    __builtin_memcpy(&f, &x, 4);
    return f;
}
__device__ __forceinline__ float fexp2(float x) {
#if __has_builtin(__builtin_amdgcn_exp2f)
    return __builtin_amdgcn_exp2f(x);
#else
    return exp2f(x);
#endif
}

// ---------------- prep: stats(high) / stats(low) / weight bf16 blocked conversion -----
// grid (64, BB, 3), block 256. z=0: stats high; z=1: stats low; z=2: wconv.
// Blocked W layout: tile (mt,kt) of 16 rows x 32 cols at ((mt*(K/32)+kt)<<9),
// element (m%16)*32 + (k%32)  -> GEMM A-frag load = 1KB contiguous per wave.
__global__ __launch_bounds__(256)
void prep_kernel(const float* __restrict__ high, const float* __restrict__ low,
                 float* __restrict__ acc,
                 const float* __restrict__ w0, const float* __restrict__ w1,
                 const float* __restrict__ w2, const float* __restrict__ w3,
                 const float* __restrict__ w4, const float* __restrict__ w5,
                 unsigned short* __restrict__ dst)
{
    const int z = blockIdx.z;
    if (z < 2) {
        const int perSample = z == 0 ? CHIGH * NN : CLOW * NN;
        const float* X = z == 0 ? high : low;
        float* ac = acc + (z == 0 ? 0 : 8);
        const int b = blockIdx.y;
        const float4* xp = (const float4*)(X + (size_t)b * perSample);
        const int n4 = perSample >> 2;
        const int stride = gridDim.x * blockDim.x;
        int i = blockIdx.x * blockDim.x + threadIdx.x;
        float s = 0.f, s2 = 0.f, sB = 0.f, s2B = 0.f;
        for (; i + stride < n4; i += 2 * stride) {
            float4 v = xp[i];
            float4 u = xp[i + stride];
            s  += v.x + v.y + v.z + v.w;
            s2 += v.x * v.x + v.y * v.y + v.z * v.z + v.w * v.w;
            sB  += u.x + u.y + u.z + u.w;
            s2B += u.x * u.x + u.y * u.y + u.z * u.z + u.w * u.w;
        }
        if (i < n4) {
            float4 v = xp[i];
            s  += v.x + v.y + v.z + v.w;
            s2 += v.x * v.x + v.y * v.y + v.z * v.z + v.w * v.w;
        }
        s += sB; s2 += s2B;
        for (int off = 32; off; off >>= 1) {
            s  += __shfl_down(s, off, 64);
            s2 += __shfl_down(s2, off, 64);
        }
        __shared__ float ls[4], ls2[4];
        const int w = threadIdx.x >> 6;
        if ((threadIdx.x & 63) == 0) { ls[w] = s; ls2[w] = s2; }
        __syncthreads();
        if (threadIdx.x == 0) {
            atomicAdd(&ac[2 * b], ls[0] + ls[1] + ls[2] + ls[3]);
            atomicAdd(&ac[2 * b + 1], ls2[0] + ls2[1] + ls2[2] + ls2[3]);
        }
    } else {
        const int idx = blockIdx.y * 64 + blockIdx.x;   // 0..255
        const int m = idx >> 5;
        if (m >= 6) return;
        const int sizes[6] = {32768, 16384, 16384, 16384, 32768, 32768};
        const int offs[6]  = {0, 32768, 49152, 65536, 81920, 114688};
        const int Ks[6]    = {256, 128, 128, 128, 128, 256};
        const float* src = m == 0 ? w0 : m == 1 ? w1 : m == 2 ? w2 : m == 3 ? w3
                         : m == 4 ? w4 : w5;
        const int i = ((idx & 31) * 256 + threadIdx.x) * 4;
        if (i >= sizes[m]) return;
        const int K = Ks[m];
        const int row = i / K, col = i % K;           // col multiple of 4
        const int mt = row >> 4, mr = row & 15;
        const int kt = col >> 5, kr = col & 31;
        float4 v = *(const float4*)&src[i];
        uint2 pk;
        pk.x = cvt_pk(v.x, v.y);
        pk.y = cvt_pk(v.z, v.w);
        const int doff = offs[m] + (((mt * (K >> 5)) + kt) << 9) + (mr << 5) + kr;
        *(uint2*)&dst[doff] = pk;
    }
}

// ---------------- fused QKV: z=0 -> Q GEMM (K=256); z=1 -> K+V GEMM (K=128) ------------
// grid (N/32, BB, 2), block 256 (4 waves). W-frags from blocked bf16 (1KB/wave).
// Staging global loads hoisted (all in flight before convert phase).
__global__ __launch_bounds__(256)
void qkv_kernel(const unsigned short* __restrict__ wbf,
                const float* __restrict__ high, const float* __restrict__ low,
                unsigned short* __restrict__ Qt, unsigned short* __restrict__ Kt,
                unsigned short* __restrict__ Vt,
                const float* __restrict__ nh_w, const float* __restrict__ nh_b,
                const float* __restrict__ nl_w, const float* __restrict__ nl_b,
                const float* __restrict__ st)
{
    __shared__ unsigned short XsRaw[32 * 264];
    const int b = blockIdx.y;
    const int n0 = blockIdx.x * 32;
    const int t = threadIdx.x;
    const int w = t >> 6, lm = t & 15, quad = (t & 63) >> 4;
    const int fo = lm * 32 + quad * 8;       // frag offset within a 512-elem W tile
    unsigned int* xw = (unsigned int*)XsRaw;

    if (blockIdx.z == 0) {
        // ---------- Q path: K = 256 ----------
        const float invCnt = 1.0f / ((float)CHIGH * NN);
        const float mean = st[2 * b] * invCnt;
        const float rstd = rsqrtf(st[2 * b + 1] * invCnt - mean * mean + EPS);
        const float* Xb = high + (size_t)b * CHIGH * NN;
        float4 ra[4], rb[4];
        float wa[4], wb_[4], ca[4], cb[4];
        #pragma unroll
        for (int it = 0; it < 4; it++) {
            const int s = it * 256 + t;
            const int kp = s >> 3;
            const int k2 = kp << 1;
            const int nc = (s & 7) << 2;
            const size_t ro = (size_t)k2 * NN + n0 + nc;
            ra[it] = *(const float4*)&Xb[ro];
            rb[it] = *(const float4*)&Xb[ro + NN];
            wa[it] = nh_w[k2]; wb_[it] = nh_w[k2 + 1];
            ca[it] = nh_b[k2]; cb[it] = nh_b[k2 + 1];
        }
        #pragma unroll
        for (int it = 0; it < 4; it++) {
            const int s = it * 256 + t;
            const int kp = s >> 3;
            const int nc = (s & 7) << 2;
            float4 pa = ra[it], pb = rb[it];
            const float sc0 = wa[it] * rstd,  sb0 = ca[it] - mean * sc0;
            const float sc1 = wb_[it] * rstd, sb1 = cb[it] - mean * sc1;
            pa.x = pa.x * sc0 + sb0; pa.y = pa.y * sc0 + sb0;
            pa.z = pa.z * sc0 + sb0; pa.w = pa.w * sc0 + sb0;
            pb.x = pb.x * sc1 + sb1; pb.y = pb.y * sc1 + sb1;
            pb.z = pb.z * sc1 + sb1; pb.w = pb.w * sc1 + sb1;
            xw[(nc + 0) * 132 + kp] = cvt_pk(pa.x, pb.x);
            xw[(nc + 1) * 132 + kp] = cvt_pk(pa.y, pb.y);
            xw[(nc + 2) * 132 + kp] = cvt_pk(pa.z, pb.z);
            xw[(nc + 3) * 132 + kp] = cvt_pk(pa.w, pb.w);
        }
        __syncthreads();
        const int ng = w & 1, mh = w >> 1;
        f4 acc[4];
        #pragma unroll
        for (int f = 0; f < 4; f++) acc[f] = (f4){0.f, 0.f, 0.f, 0.f};
        #pragma unroll
        for (int kc = 0; kc < 8; kc++) {
            b8 bx = *(const b8*)&XsRaw[(ng * 16 + lm) * 264 + kc * 32 + quad * 8];
            #pragma unroll
            for (int f = 0; f < 4; f++) {
                b8 af = *(const b8*)&wbf[(((mh * 4 + f) * 8 + kc) << 9) + fo];
                acc[f] = __builtin_amdgcn_mfma_f32_16x16x32_bf16(af, bx, acc[f], 0, 0, 0);
            }
        }
        const int n = n0 + ng * 16 + lm;
        const float oscale = 0.25503480f;   // 32^-0.5 * log2(e)
        #pragma unroll
        for (int f = 0; f < 4; f++) {
            const int mb = mh * 64 + f * 16 + quad * 4;
            const int hh = mb >> 5, ddb = mb & 31;
            uint2 pk;
            pk.x = cvt_pk(acc[f][0] * oscale, acc[f][1] * oscale);
            pk.y = cvt_pk(acc[f][2] * oscale, acc[f][3] * oscale);
            *(uint2*)&Qt[((size_t)(b * NHEADS + hh) * NN + n) * 32 + ddb] = pk;
        }
    } else {
        // ---------- KV path: stacked Wk(tiles 0..31)+Wv(32..63) blocked at +32768 ------
        const unsigned short* Wb = wbf + 32768;
        const float invCnt = 1.0f / ((float)CLOW * NN);
        const float mean = st[8 + 2 * b] * invCnt;
        const float rstd = rsqrtf(st[8 + 2 * b + 1] * invCnt - mean * mean + EPS);
        const float* Xb = low + (size_t)b * CLOW * NN;
        float4 ra[2], rb[2];
        float wa[2], wb_[2], ca[2], cb[2];
        #pragma unroll
        for (int it = 0; it < 2; it++) {
            const int s = it * 256 + t;
            const int kp = s >> 3;
            const int k2 = kp << 1;
            const int nc = (s & 7) << 2;
            const size_t ro = (size_t)k2 * NN + n0 + nc;
            ra[it] = *(const float4*)&Xb[ro];
            rb[it] = *(const float4*)&Xb[ro + NN];
            wa[it] = nl_w[k2]; wb_[it] = nl_w[k2 + 1];
            ca[it] = nl_b[k2]; cb[it] = nl_b[k2 + 1];
        }
        #pragma unroll
        for (int it = 0; it < 2; it++) {
            const int s = it * 256 + t;
            const int kp = s >> 3;
            const int nc = (s & 7) << 2;
            float4 pa = ra[it], pb = rb[it];
            const float sc0 = wa[it] * rstd,  sb0 = ca[it] - mean * sc0;
            const float sc1 = wb_[it] * rstd, sb1 = cb[it] - mean * sc1;
            pa.x = pa.x * sc0 + sb0; pa.y = pa.y * sc0 + sb0;
            pa.z = pa.z * sc0 + sb0; pa.w = pa.w * sc0 + sb0;
            pb.x = pb.x * sc1 + sb1; pb.y = pb.y * sc1 + sb1;
            pb.z = pb.z * sc1 + sb1; pb.w = pb.w * sc1 + sb1;
            xw[(nc + 0) * 68 + kp] = cvt_pk(pa.x, pb.x);
            xw[(nc + 1) * 68 + kp] = cvt_pk(pa.y, pb.y);
            xw[(nc + 2) * 68 + kp] = cvt_pk(pa.z, pb.z);
            xw[(nc + 3) * 68 + kp] = cvt_pk(pa.w, pb.w);
        }
        __syncthreads();
        f4 acc[2][4];
        #pragma unroll
        for (int ng = 0; ng < 2; ng++)
            #pragma unroll
            for (int f = 0; f < 4; f++) acc[ng][f] = (f4){0.f, 0.f, 0.f, 0.f};
        #pragma unroll
        for (int kc = 0; kc < 4; kc++) {
            b8 bx0 = *(const b8*)&XsRaw[lm * 136 + kc * 32 + quad * 8];
            b8 bx1 = *(const b8*)&XsRaw[(16 + lm) * 136 + kc * 32 + quad * 8];
            #pragma unroll
            for (int f = 0; f < 4; f++) {
                b8 af = *(const b8*)&Wb[(((w * 4 + f) * 4 + kc) << 9) + fo];
                acc[0][f] = __builtin_amdgcn_mfma_f32_16x16x32_bf16(af, bx0, acc[0][f], 0, 0, 0);
                acc[1][f] = __builtin_amdgcn_mfma_f32_16x16x32_bf16(af, bx1, acc[1][f], 0, 0, 0);
            }
        }
        if (w < 2) {
            #pragma unroll
            for (int ng = 0; ng < 2; ng++) {
                const int n = n0 + ng * 16 + lm;
                #pragma unroll
                for (int f = 0; f < 4; f++) {
                    const int mb = w * 64 + f * 16 + quad * 4;
                    const int hh = mb >> 5, ddb = mb & 31;
                    uint2 pk;
                    pk.x = cvt_pk(acc[ng][f][0], acc[ng][f][1]);
                    pk.y = cvt_pk(acc[ng][f][2], acc[ng][f][3]);
                    *(uint2*)&Kt[((size_t)(b * NHEADS + hh) * NN + n) * 32 + ddb] = pk;
                }
            }
        } else {
            #pragma unroll
            for (int ng = 0; ng < 2; ng++) {
                const int n = n0 + ng * 16 + lm;
                const size_t nblk = ((size_t)(n >> 5) << 10) + (n & 31);
                #pragma unroll
                for (int f = 0; f < 4; f++) {
                    const int db = (w - 2) * 64 + f * 16 + quad * 4;
                    const int hh = db >> 5;
                    const size_t hb = (size_t)(b * NHEADS + hh) * NN * 32;
                    #pragma unroll
                    for (int r = 0; r < 4; r++) {
                        const int d = (db + r) & 31;
                        unsigned int u = cvt_pk(acc[ng][f][r], 0.f);
                        Vt[hb + nblk + (size_t)d * 32] = (unsigned short)(u & 0xFFFF);
                    }
                }
            }
        }
    }
}

// ---------------- Flash attention: XCD-local groups, K-prefetch pipeline --------------
// Qt/Kt bf16 [B][NH][N][32], Vt bf16 blocked. flat grid 1024, block 512.
// K frags ping-pong one tile ahead (+16 VGPR, <=64 total keeps 8 waves/SIMD);
// V frags load in-loop (natural QK+exp slack before PV). NO barrier in K-loop.
__global__ __launch_bounds__(512, 8)
void flash_kernel(const unsigned short* __restrict__ Qt,
                  const unsigned short* __restrict__ Kt,
                  const unsigned short* __restrict__ Vt,
                  unsigned short* __restrict__ Op, float* __restrict__ Lp)
{
    __shared__ unsigned short Ps[8][32][72];

    const int lid = blockIdx.x;
    const int xcd = lid & 7, slot = lid >> 3;       // 128 slots per XCD
    const int g = xcd * 8 + (slot >> 4);            // 64 groups, 8 per XCD
    const int xblk = slot & 15;
    const int half = g >> 4, bh = g & 15;
    const int b = bh >> 2, h = bh & 3;
    const int n0 = xblk * 256;
    const int t = threadIdx.x;
    const int w = t >> 6;                           // 0..7
    const int lm = t & 15, quad = (t & 63) >> 4;

    const unsigned short* Qh = Qt + (size_t)(b * NHEADS + h) * NN * 32;
    const unsigned short* Kh = Kt + (size_t)(b * NHEADS + h) * NN * 32;
    const unsigned short* Vh = Vt + (size_t)(b * NHEADS + h) * NN * 32;

    b8 aq[2];
    aq[0] = *(const b8*)&Qh[(size_t)(n0 + w * 32 + lm) * 32 + quad * 8];
    aq[1] = *(const b8*)&Qh[(size_t)(n0 + w * 32 + 16 + lm) * 32 + quad * 8];

    b8 ones;
    #pragma unroll
    for (int j = 0; j < 8; j++) ones[j] = (__bf16)1.0f;

    f4 ocT[2][2];
    f4 lsum[2];
    #pragma unroll
    for (int u = 0; u < 2; u++) {
        lsum[u] = (f4){0.f, 0.f, 0.f, 0.f};
        ocT[0][u] = (f4){0.f, 0.f, 0.f, 0.f};
        ocT[1][u] = (f4){0.f, 0.f, 0.f, 0.f};
    }

    auto loadK = [&](int m0, b8* bk) {
        #pragma unroll
        for (int f = 0; f < 4; f++)
            bk[f] = *(const b8*)&Kh[(size_t)(m0 + f * 16 + lm) * 32 + quad * 8];
    };
    auto tile = [&](int m0, const b8* bk) {
        b8 av[2][2];
        #pragma unroll
        for (int c = 0; c < 2; c++) {
            const size_t vb = (size_t)(m0 + c * 32) * 32 + quad * 8;
            av[0][c] = *(const b8*)&Vh[vb + (size_t)lm * 32];
            av[1][c] = *(const b8*)&Vh[vb + (size_t)(16 + lm) * 32];
        }
        #pragma unroll
        for (int f = 0; f < 4; f++)
            #pragma unroll
            for (int u = 0; u < 2; u++) {
                f4 z = {0.f, 0.f, 0.f, 0.f};
                f4 sv = __builtin_amdgcn_mfma_f32_16x16x32_bf16(bk[f], aq[u], z, 0, 0, 0);
                uint2 pk;
                pk.x = cvt_pk(fexp2(sv[0]), fexp2(sv[1]));
                pk.y = cvt_pk(fexp2(sv[2]), fexp2(sv[3]));
                *(uint2*)&Ps[w][u * 16 + lm][f * 16 + quad * 4] = pk;
            }
        #pragma unroll
        for (int c = 0; c < 2; c++)
            #pragma unroll
            for (int u = 0; u < 2; u++) {
                b8 bp = *(const b8*)&Ps[w][u * 16 + lm][c * 32 + quad * 8];
                ocT[0][u] = __builtin_amdgcn_mfma_f32_16x16x32_bf16(av[0][c], bp, ocT[0][u], 0, 0, 0);
                ocT[1][u] = __builtin_amdgcn_mfma_f32_16x16x32_bf16(av[1][c], bp, ocT[1][u], 0, 0, 0);
                lsum[u]   = __builtin_amdgcn_mfma_f32_16x16x32_bf16(ones, bp, lsum[u], 0, 0, 0);
            }
    };

    const int m_lo = half * (NN / SPLITS);
    constexpr int nT = NN / SPLITS / 64;            // 16 (even)
    b8 bkA[4], bkB[4];
    loadK(m_lo, bkA);
    for (int it = 0; it < nT; it += 2) {
        loadK(m_lo + (it + 1) * 64, bkB);           // prefetch K for odd tile
        tile(m_lo + it * 64, bkA);
        const int m2 = (it + 2 < nT) ? m_lo + (it + 2) * 64 : m_lo;
        loadK(m2, bkA);                             // prefetch K for next even tile
        tile(m_lo + (it + 1) * 64, bkB);
    }

    unsigned short* OpB = Op + ((size_t)(half * BB + b) * CLOW + h * HDIM) * NN;
    float* LpB = Lp + ((size_t)(half * BB + b) * NHEADS + h) * NN;
    #pragma unroll
    for (int u = 0; u < 2; u++) {
        const int n = n0 + w * 32 + u * 16 + lm;
        if (quad == 0) LpB[n] = lsum[u][0];
        #pragma unroll
        for (int hh = 0; hh < 2; hh++)
            #pragma unroll
            for (int r = 0; r < 4; r++) {
                const int d = hh * 16 + quad * 4 + r;
                unsigned int uu = cvt_pk(ocT[hh][u][r], 0.f);
                OpB[(size_t)d * NN + n] = (unsigned short)(uu & 0xFFFF);
            }
    }
}

// ---------------- proj: x = low + g*(Wproj @ combine(opart,lpart)); + x stats --------
// grid (N/32, B), block 256 (4 waves; wave -> 32 m rows x both 16n groups).
// Full M=128 per block: combine staging done ONCE (was duplicated across 2 m-blocks).
__global__ __launch_bounds__(256)
void proj_kernel(const unsigned short* __restrict__ Wb,
                 const unsigned short* __restrict__ Opart, const float* __restrict__ Lp,
                 const float* __restrict__ low, float* __restrict__ Xout,
                 const float* __restrict__ gp, float* __restrict__ stOut)
{
    __shared__ unsigned short Xs[32][136];
    __shared__ float red[8];
    const int b = blockIdx.y;
    const int n0 = blockIdx.x * 32;
    const int t = threadIdx.x;
    const int w = t >> 6, lm = t & 15, quad = (t & 63) >> 4;
    const int fo = lm * 32 + quad * 8;
    unsigned int* xw = (unsigned int*)&Xs[0][0];

    #pragma unroll
    for (int it = 0; it < 2; it++) {
        const int s = it * 256 + t;
        const int kp = s >> 3;
        const int k2 = kp << 1;
        const int nc = (s & 7) << 2;
        const size_t ro = (size_t)k2 * NN + n0 + nc;
        const int hh = k2 >> 5;
        const size_t lo = (size_t)(b * NHEADS + hh) * NN + n0 + nc;
        float4 l4 = *(const float4*)&Lp[lo];
        #pragma unroll
        for (int sp = 1; sp < SPLITS; sp++)
            l4 += *(const float4*)&Lp[lo + (size_t)sp * BB * NHEADS * NN];
        float4 pa = {0.f, 0.f, 0.f, 0.f}, pb = {0.f, 0.f, 0.f, 0.f};
        #pragma unroll
        for (int sp = 0; sp < SPLITS; sp++) {
            const unsigned short* Os = Opart + (size_t)sp * BB * CLOW * NN
                                     + (size_t)b * CLOW * NN + ro;
            ushort4 ua = *(const ushort4*)Os;
            ushort4 ub = *(const ushort4*)(Os + NN);
            pa.x += b2f(ua.x); pa.y += b2f(ua.y); pa.z += b2f(ua.z); pa.w += b2f(ua.w);
            pb.x += b2f(ub.x); pb.y += b2f(ub.y); pb.z += b2f(ub.z); pb.w += b2f(ub.w);
        }
        float4 iv;
        iv.x = 1.f / l4.x; iv.y = 1.f / l4.y; iv.z = 1.f / l4.z; iv.w = 1.f / l4.w;
        pa.x *= iv.x; pa.y *= iv.y; pa.z *= iv.z; pa.w *= iv.w;
        pb.x *= iv.x; pb.y *= iv.y; pb.z *= iv.z; pb.w *= iv.w;
        xw[(nc + 0) * 68 + kp] = cvt_pk(pa.x, pb.x);
        xw[(nc + 1) * 68 + kp] = cvt_pk(pa.y, pb.y);
        xw[(nc + 2) * 68 + kp] = cvt_pk(pa.z, pb.z);
        xw[(nc + 3) * 68 + kp] = cvt_pk(pa.w, pb.w);
    }
    __syncthreads();

    f4 acc[2][2];   // [f m-tile][ng n-group]
    #pragma unroll
    for (int f = 0; f < 2; f++) {
        acc[f][0] = (f4){0.f, 0.f, 0.f, 0.f};
        acc[f][1] = (f4){0.f, 0.f, 0.f, 0.f};
    }
    #pragma unroll
    for (int kc = 0; kc < 4; kc++) {
        b8 bx0 = *(const b8*)&Xs[lm][kc * 32 + quad * 8];
        b8 bx1 = *(const b8*)&Xs[16 + lm][kc * 32 + quad * 8];
        #pragma unroll
        for (int f = 0; f < 2; f++) {
            const int mt = w * 2 + f;
            b8 af = *(const b8*)&Wb[((mt * 4 + kc) << 9) + fo];
            acc[f][0] = __builtin_amdgcn_mfma_f32_16x16x32_bf16(af, bx0, acc[f][0], 0, 0, 0);
            acc[f][1] = __builtin_amdgcn_mfma_f32_16x16x32_bf16(af, bx1, acc[f][1], 0, 0, 0);
        }
    }

    const float g = gp[0];
    const float* Rb = low + (size_t)b * CLOW * NN;
    float* Yb = Xout + (size_t)b * CLOW * NN;
    float s = 0.f, s2 = 0.f;
    #pragma unroll
    for (int f = 0; f < 2; f++)
        #pragma unroll
        for (int ng = 0; ng < 2; ng++) {
            const int n = n0 + ng * 16 + lm;
            #pragma unroll
            for (int r = 0; r < 4; r++) {
                const int m = w * 32 + f * 16 + quad * 4 + r;
                const size_t off = (size_t)m * NN + n;
                float v = Rb[off] + g * acc[f][ng][r];
                Yb[off] = v;
                s += v; s2 += v * v;
            }
        }
    for (int off = 32; off; off >>= 1) {
        s  += __shfl_down(s, off, 64);
        s2 += __shfl_down(s2, off, 64);
    }
    if ((t & 63) == 0) { red[w] = s; red[4 + w] = s2; }
    __syncthreads();
    if (t == 0) {
        atomicAdd(&stOut[2 * b], red[0] + red[1] + red[2] + red[3]);
        atomicAdd(&stOut[2 * b + 1], red[4] + red[5] + red[6] + red[7]);
    }
}

// ---------------- fused FFN: out = x + g * (W2 @ gelu(W1 @ norm(x))) ----------------
// grid (N/32, B), block 512 (8 waves). H strip [256][32n] in LDS. Blocked W.
__global__ __launch_bounds__(512)
void ffn_kernel(const unsigned short* __restrict__ W1, const unsigned short* __restrict__ W2,
                const float* __restrict__ X, float* __restrict__ Out,
                const float* __restrict__ nw, const float* __restrict__ nb,
                const float* __restrict__ st, const float* __restrict__ gp)
{
    __shared__ unsigned short Xs[32][136];
    __shared__ unsigned short Hs[32][264];
    const int b = blockIdx.y;
    const int n0 = blockIdx.x * 32;
    const int t = threadIdx.x;
    const int w = t >> 6, lm = t & 15, quad = (t & 63) >> 4;
    const int fo = lm * 32 + quad * 8;

    const float invCnt = 1.0f / ((float)CLOW * NN);
    const float mean = st[2 * b] * invCnt;
    const float rstd = rsqrtf(st[2 * b + 1] * invCnt - mean * mean + EPS);

    const float* Xb = X + (size_t)b * CLOW * NN;
    unsigned int* xw = (unsigned int*)&Xs[0][0];
    {
        const int s = t;
        const int kp = s >> 3;
        const int k2 = kp << 1;
        const int nc = (s & 7) << 2;
        const size_t ro = (size_t)k2 * NN + n0 + nc;
        float4 pa = *(const float4*)&Xb[ro];
        float4 pb = *(const float4*)&Xb[ro + NN];
        const float sc0 = nw[k2] * rstd,     sb0 = nb[k2] - mean * sc0;
        const float sc1 = nw[k2 + 1] * rstd, sb1 = nb[k2 + 1] - mean * sc1;
        pa.x = pa.x * sc0 + sb0; pa.y = pa.y * sc0 + sb0;
        pa.z = pa.z * sc0 + sb0; pa.w = pa.w * sc0 + sb0;
        pb.x = pb.x * sc1 + sb1; pb.y = pb.y * sc1 + sb1;
        pb.z = pb.z * sc1 + sb1; pb.w = pb.w * sc1 + sb1;
        xw[(nc + 0) * 68 + kp] = cvt_pk(pa.x, pb.x);
        xw[(nc + 1) * 68 + kp] = cvt_pk(pa.y, pb.y);
        xw[(nc + 2) * 68 + kp] = cvt_pk(pa.z, pb.z);
        xw[(nc + 3) * 68 + kp] = cvt_pk(pa.w, pb.w);
    }
    __syncthreads();

    // phase1: wave w computes H rows w*32..+32 for both 16n groups
    f4 hv[2][2];
    #pragma unroll
    for (int ng = 0; ng < 2; ng++) {
        hv[ng][0] = (f4){0.f, 0.f, 0.f, 0.f};
        hv[ng][1] = (f4){0.f, 0.f, 0.f, 0.f};
    }
    #pragma unroll
    for (int kc = 0; kc < 4; kc++) {
        b8 bx0 = *(const b8*)&Xs[lm][kc * 32 + quad * 8];
        b8 bx1 = *(const b8*)&Xs[16 + lm][kc * 32 + quad * 8];
        #pragma unroll
        for (int f = 0; f < 2; f++) {
            const int mt = w * 2 + f;
            b8 af = *(const b8*)&W1[((mt * 4 + kc) << 9) + fo];
            hv[0][f] = __builtin_amdgcn_mfma_f32_16x16x32_bf16(af, bx0, hv[0][f], 0, 0, 0);
            hv[1][f] = __builtin_amdgcn_mfma_f32_16x16x32_bf16(af, bx1, hv[1][f], 0, 0, 0);
        }
    }
    #pragma unroll
    for (int ng = 0; ng < 2; ng++)
        #pragma unroll
        for (int f = 0; f < 2; f++) {
            float g0 = hv[ng][f][0], g1 = hv[ng][f][1];
            float g2 = hv[ng][f][2], g3 = hv[ng][f][3];
            g0 = 0.5f * g0 * (1.f + erff(g0 * 0.70710678118654752f));
            g1 = 0.5f * g1 * (1.f + erff(g1 * 0.70710678118654752f));
            g2 = 0.5f * g2 * (1.f + erff(g2 * 0.70710678118654752f));
            g3 = 0.5f * g3 * (1.f + erff(g3 * 0.70710678118654752f));
            uint2 pk;
            pk.x = cvt_pk(g0, g1);
            pk.y = cvt_pk(g2, g3);
            *(uint2*)&Hs[ng * 16 + lm][w * 32 + f * 16 + quad * 4] = pk;
        }
    __syncthreads();

    // phase2: wave w computes out rows w*16..+16 for both 16n groups
    f4 o[2];
    o[0] = (f4){0.f, 0.f, 0.f, 0.f};
    o[1] = (f4){0.f, 0.f, 0.f, 0.f};
    #pragma unroll
    for (int kc = 0; kc < 8; kc++) {
        b8 bh0 = *(const b8*)&Hs[lm][kc * 32 + quad * 8];
        b8 bh1 = *(const b8*)&Hs[16 + lm][kc * 32 + quad * 8];
        b8 af = *(const b8*)&W2[((w * 8 + kc) << 9) + fo];
        o[0] = __builtin_amdgcn_mfma_f32_16x16x32_bf16(af, bh0, o[0], 0, 0, 0);
        o[1] = __builtin_amdgcn_mfma_f32_16x16x32_bf16(af, bh1, o[1], 0, 0, 0);
    }
    const float g = gp[0];
    float* Ob = Out + (size_t)b * CLOW * NN;
    #pragma unroll
    for (int ng = 0; ng < 2; ng++) {
        const int n = n0 + ng * 16 + lm;
        #pragma unroll
        for (int r = 0; r < 4; r++) {
            const int m = w * 16 + quad * 4 + r;
            const size_t off = (size_t)m * NN + n;
            Ob[off] = Xb[off] + g * o[ng][r];
        }
    }
}

extern "C" void kernel_launch(void* const* d_in, const int* in_sizes, int n_in,
                              void* d_out, int out_size, void* d_ws, size_t ws_size,
                              hipStream_t stream)
{
    const float* high  = (const float*)d_in[0];
    const float* low   = (const float*)d_in[1];
    const float* nh_w  = (const float*)d_in[2];
    const float* nh_b  = (const float*)d_in[3];
    const float* nl_w  = (const float*)d_in[4];
    const float* nl_b  = (const float*)d_in[5];
    const float* nf_w  = (const float*)d_in[6];
    const float* nf_b  = (const float*)d_in[7];
    const float* Wq    = (const float*)d_in[8];
    const float* Wk    = (const float*)d_in[9];
    const float* Wv    = (const float*)d_in[10];
    const float* Wproj = (const float*)d_in[11];
    const float* Wff1  = (const float*)d_in[12];
    const float* Wff2  = (const float*)d_in[13];
    const float* g_at  = (const float*)d_in[14];
    const float* g_ff  = (const float*)d_in[15];
    float* out = (float*)d_out;

    float* ws    = (float*)d_ws;
    float* stats = ws;                                       // 64 floats
    unsigned short* wbf = (unsigned short*)(ws + 64);        // 147456 bf16 weights (blocked)
    unsigned short* qt = wbf + 147456;                       // [B][NH][NN][32] bf16
    unsigned short* kt = qt + (size_t)BB * NHEADS * NN * 32;
    unsigned short* vt = kt + (size_t)BB * NHEADS * NN * 32; // blocked bf16
    unsigned short* opart = vt + (size_t)BB * CLOW * NN;     // [SPLITS][B][CLOW][NN] bf16
    float* lpart = (float*)(opart + (size_t)SPLITS * BB * CLOW * NN);
    float* x     = lpart + (size_t)SPLITS * BB * NHEADS * NN;

    (void)hipMemsetAsync(stats, 0, 64 * sizeof(float), stream);

    prep_kernel<<<dim3(64, BB, 3), 256, 0, stream>>>(high, low, stats,
                                                     Wq, Wk, Wv, Wproj, Wff1, Wff2, wbf);

    qkv_kernel<<<dim3(128, BB, 2), 256, 0, stream>>>(wbf, high, low, qt, kt, vt,
                                                     nh_w, nh_b, nl_w, nl_b, stats);

    flash_kernel<<<dim3(1024), 512, 0, stream>>>(qt, kt, vt, opart, lpart);

    proj_kernel<<<dim3(128, BB), 256, 0, stream>>>(wbf + 65536, opart, lpart,
                                                   low, x, g_at, stats + 16);

    ffn_kernel<<<dim3(128, BB), 512, 0, stream>>>(wbf + 81920, wbf + 114688, x, out,
                                                  nf_w, nf_b, stats + 16, g_ff);
}

// Round 13
// 220.113 us; speedup vs baseline: 1.4793x; 1.4793x over previous
//
#include <hip/hip_runtime.h>
#include <hip/hip_bf16.h>
#include <math.h>

#define EPS 1e-5f
#define BB 4
#define CHIGH 256
#define CLOW 128
#define NN 4096
#define NHEADS 4
#define HDIM 32
#define FFN_DIM 256
#define SPLITS 4

typedef __bf16 b8 __attribute__((ext_vector_type(8)));
typedef float f4 __attribute__((ext_vector_type(4)));

__device__ __forceinline__ unsigned int cvt_pk(float lo, float hi) {
    float2 t; t.x = lo; t.y = hi;
    __hip_bfloat162 h = __float22bfloat162_rn(t);
    unsigned int r;
    __builtin_memcpy(&r, &h, sizeof(r));
    return r;
}
__device__ __forceinline__ float b2f(unsigned short u) {
    unsigned int x = ((unsigned int)u) << 16;
    float f;
    __builtin_memcpy(&f, &x, 4);
    return f;
}
__device__ __forceinline__ float fexp2(float x) {
#if __has_builtin(__builtin_amdgcn_exp2f)
    return __builtin_amdgcn_exp2f(x);
#else
    return exp2f(x);
#endif
}

// ---------------- prep: stats(high) / stats(low) / weight bf16 blocked conversion -----
// grid (64, BB, 3), block 256. z=0: stats high; z=1: stats low; z=2: wconv.
// Blocked W layout: tile (mt,kt) of 16 rows x 32 cols at ((mt*(K/32)+kt)<<9),
// element (m%16)*32 + (k%32)  -> GEMM A-frag load = 1KB contiguous per wave.
__global__ __launch_bounds__(256)
void prep_kernel(const float* __restrict__ high, const float* __restrict__ low,
                 float* __restrict__ acc,
                 const float* __restrict__ w0, const float* __restrict__ w1,
                 const float* __restrict__ w2, const float* __restrict__ w3,
                 const float* __restrict__ w4, const float* __restrict__ w5,
                 unsigned short* __restrict__ dst)
{
    const int z = blockIdx.z;
    if (z < 2) {
        const int perSample = z == 0 ? CHIGH * NN : CLOW * NN;
        const float* X = z == 0 ? high : low;
        float* ac = acc + (z == 0 ? 0 : 8);
        const int b = blockIdx.y;
        const float4* xp = (const float4*)(X + (size_t)b * perSample);
        const int n4 = perSample >> 2;
        const int stride = gridDim.x * blockDim.x;
        int i = blockIdx.x * blockDim.x + threadIdx.x;
        float s = 0.f, s2 = 0.f, sB = 0.f, s2B = 0.f;
        for (; i + stride < n4; i += 2 * stride) {
            float4 v = xp[i];
            float4 u = xp[i + stride];
            s  += v.x + v.y + v.z + v.w;
            s2 += v.x * v.x + v.y * v.y + v.z * v.z + v.w * v.w;
            sB  += u.x + u.y + u.z + u.w;
            s2B += u.x * u.x + u.y * u.y + u.z * u.z + u.w * u.w;
        }
        if (i < n4) {
            float4 v = xp[i];
            s  += v.x + v.y + v.z + v.w;
            s2 += v.x * v.x + v.y * v.y + v.z * v.z + v.w * v.w;
        }
        s += sB; s2 += s2B;
        for (int off = 32; off; off >>= 1) {
            s  += __shfl_down(s, off, 64);
            s2 += __shfl_down(s2, off, 64);
        }
        __shared__ float ls[4], ls2[4];
        const int w = threadIdx.x >> 6;
        if ((threadIdx.x & 63) == 0) { ls[w] = s; ls2[w] = s2; }
        __syncthreads();
        if (threadIdx.x == 0) {
            atomicAdd(&ac[2 * b], ls[0] + ls[1] + ls[2] + ls[3]);
            atomicAdd(&ac[2 * b + 1], ls2[0] + ls2[1] + ls2[2] + ls2[3]);
        }
    } else {
        const int idx = blockIdx.y * 64 + blockIdx.x;   // 0..255
        const int m = idx >> 5;
        if (m >= 6) return;
        const int sizes[6] = {32768, 16384, 16384, 16384, 32768, 32768};
        const int offs[6]  = {0, 32768, 49152, 65536, 81920, 114688};
        const int Ks[6]    = {256, 128, 128, 128, 128, 256};
        const float* src = m == 0 ? w0 : m == 1 ? w1 : m == 2 ? w2 : m == 3 ? w3
                         : m == 4 ? w4 : w5;
        const int i = ((idx & 31) * 256 + threadIdx.x) * 4;
        if (i >= sizes[m]) return;
        const int K = Ks[m];
        const int row = i / K, col = i % K;           // col multiple of 4
        const int mt = row >> 4, mr = row & 15;
        const int kt = col >> 5, kr = col & 31;
        float4 v = *(const float4*)&src[i];
        uint2 pk;
        pk.x = cvt_pk(v.x, v.y);
        pk.y = cvt_pk(v.z, v.w);
        const int doff = offs[m] + (((mt * (K >> 5)) + kt) << 9) + (mr << 5) + kr;
        *(uint2*)&dst[doff] = pk;
    }
}

// ---------------- fused QKV: z=0 -> Q GEMM (K=256); z=1 -> K+V GEMM (K=128) ------------
// grid (N/32, BB, 2), block 256 (4 waves). W-frags from blocked bf16 (1KB/wave).
// Staging global loads hoisted (all in flight before convert phase).
__global__ __launch_bounds__(256)
void qkv_kernel(const unsigned short* __restrict__ wbf,
                const float* __restrict__ high, const float* __restrict__ low,
                unsigned short* __restrict__ Qt, unsigned short* __restrict__ Kt,
                unsigned short* __restrict__ Vt,
                const float* __restrict__ nh_w, const float* __restrict__ nh_b,
                const float* __restrict__ nl_w, const float* __restrict__ nl_b,
                const float* __restrict__ st)
{
    __shared__ unsigned short XsRaw[32 * 264];
    const int b = blockIdx.y;
    const int n0 = blockIdx.x * 32;
    const int t = threadIdx.x;
    const int w = t >> 6, lm = t & 15, quad = (t & 63) >> 4;
    const int fo = lm * 32 + quad * 8;       // frag offset within a 512-elem W tile
    unsigned int* xw = (unsigned int*)XsRaw;

    if (blockIdx.z == 0) {
        // ---------- Q path: K = 256 ----------
        const float invCnt = 1.0f / ((float)CHIGH * NN);
        const float mean = st[2 * b] * invCnt;
        const float rstd = rsqrtf(st[2 * b + 1] * invCnt - mean * mean + EPS);
        const float* Xb = high + (size_t)b * CHIGH * NN;
        float4 ra[4], rb[4];
        float wa[4], wb_[4], ca[4], cb[4];
        #pragma unroll
        for (int it = 0; it < 4; it++) {
            const int s = it * 256 + t;
            const int kp = s >> 3;
            const int k2 = kp << 1;
            const int nc = (s & 7) << 2;
            const size_t ro = (size_t)k2 * NN + n0 + nc;
            ra[it] = *(const float4*)&Xb[ro];
            rb[it] = *(const float4*)&Xb[ro + NN];
            wa[it] = nh_w[k2]; wb_[it] = nh_w[k2 + 1];
            ca[it] = nh_b[k2]; cb[it] = nh_b[k2 + 1];
        }
        #pragma unroll
        for (int it = 0; it < 4; it++) {
            const int s = it * 256 + t;
            const int kp = s >> 3;
            const int nc = (s & 7) << 2;
            float4 pa = ra[it], pb = rb[it];
            const float sc0 = wa[it] * rstd,  sb0 = ca[it] - mean * sc0;
            const float sc1 = wb_[it] * rstd, sb1 = cb[it] - mean * sc1;
            pa.x = pa.x * sc0 + sb0; pa.y = pa.y * sc0 + sb0;
            pa.z = pa.z * sc0 + sb0; pa.w = pa.w * sc0 + sb0;
            pb.x = pb.x * sc1 + sb1; pb.y = pb.y * sc1 + sb1;
            pb.z = pb.z * sc1 + sb1; pb.w = pb.w * sc1 + sb1;
            xw[(nc + 0) * 132 + kp] = cvt_pk(pa.x, pb.x);
            xw[(nc + 1) * 132 + kp] = cvt_pk(pa.y, pb.y);
            xw[(nc + 2) * 132 + kp] = cvt_pk(pa.z, pb.z);
            xw[(nc + 3) * 132 + kp] = cvt_pk(pa.w, pb.w);
        }
        __syncthreads();
        const int ng = w & 1, mh = w >> 1;
        f4 acc[4];
        #pragma unroll
        for (int f = 0; f < 4; f++) acc[f] = (f4){0.f, 0.f, 0.f, 0.f};
        #pragma unroll
        for (int kc = 0; kc < 8; kc++) {
            b8 bx = *(const b8*)&XsRaw[(ng * 16 + lm) * 264 + kc * 32 + quad * 8];
            #pragma unroll
            for (int f = 0; f < 4; f++) {
                b8 af = *(const b8*)&wbf[(((mh * 4 + f) * 8 + kc) << 9) + fo];
                acc[f] = __builtin_amdgcn_mfma_f32_16x16x32_bf16(af, bx, acc[f], 0, 0, 0);
            }
        }
        const int n = n0 + ng * 16 + lm;
        const float oscale = 0.25503480f;   // 32^-0.5 * log2(e)
        #pragma unroll
        for (int f = 0; f < 4; f++) {
            const int mb = mh * 64 + f * 16 + quad * 4;
            const int hh = mb >> 5, ddb = mb & 31;
            uint2 pk;
            pk.x = cvt_pk(acc[f][0] * oscale, acc[f][1] * oscale);
            pk.y = cvt_pk(acc[f][2] * oscale, acc[f][3] * oscale);
            *(uint2*)&Qt[((size_t)(b * NHEADS + hh) * NN + n) * 32 + ddb] = pk;
        }
    } else {
        // ---------- KV path: stacked Wk(tiles 0..31)+Wv(32..63) blocked at +32768 ------
        const unsigned short* Wb = wbf + 32768;
        const float invCnt = 1.0f / ((float)CLOW * NN);
        const float mean = st[8 + 2 * b] * invCnt;
        const float rstd = rsqrtf(st[8 + 2 * b + 1] * invCnt - mean * mean + EPS);
        const float* Xb = low + (size_t)b * CLOW * NN;
        float4 ra[2], rb[2];
        float wa[2], wb_[2], ca[2], cb[2];
        #pragma unroll
        for (int it = 0; it < 2; it++) {
            const int s = it * 256 + t;
            const int kp = s >> 3;
            const int k2 = kp << 1;
            const int nc = (s & 7) << 2;
            const size_t ro = (size_t)k2 * NN + n0 + nc;
            ra[it] = *(const float4*)&Xb[ro];
            rb[it] = *(const float4*)&Xb[ro + NN];
            wa[it] = nl_w[k2]; wb_[it] = nl_w[k2 + 1];
            ca[it] = nl_b[k2]; cb[it] = nl_b[k2 + 1];
        }
        #pragma unroll
        for (int it = 0; it < 2; it++) {
            const int s = it * 256 + t;
            const int kp = s >> 3;
            const int nc = (s & 7) << 2;
            float4 pa = ra[it], pb = rb[it];
            const float sc0 = wa[it] * rstd,  sb0 = ca[it] - mean * sc0;
            const float sc1 = wb_[it] * rstd, sb1 = cb[it] - mean * sc1;
            pa.x = pa.x * sc0 + sb0; pa.y = pa.y * sc0 + sb0;
            pa.z = pa.z * sc0 + sb0; pa.w = pa.w * sc0 + sb0;
            pb.x = pb.x * sc1 + sb1; pb.y = pb.y * sc1 + sb1;
            pb.z = pb.z * sc1 + sb1; pb.w = pb.w * sc1 + sb1;
            xw[(nc + 0) * 68 + kp] = cvt_pk(pa.x, pb.x);
            xw[(nc + 1) * 68 + kp] = cvt_pk(pa.y, pb.y);
            xw[(nc + 2) * 68 + kp] = cvt_pk(pa.z, pb.z);
            xw[(nc + 3) * 68 + kp] = cvt_pk(pa.w, pb.w);
        }
        __syncthreads();
        f4 acc[2][4];
        #pragma unroll
        for (int ng = 0; ng < 2; ng++)
            #pragma unroll
            for (int f = 0; f < 4; f++) acc[ng][f] = (f4){0.f, 0.f, 0.f, 0.f};
        #pragma unroll
        for (int kc = 0; kc < 4; kc++) {
            b8 bx0 = *(const b8*)&XsRaw[lm * 136 + kc * 32 + quad * 8];
            b8 bx1 = *(const b8*)&XsRaw[(16 + lm) * 136 + kc * 32 + quad * 8];
            #pragma unroll
            for (int f = 0; f < 4; f++) {
                b8 af = *(const b8*)&Wb[(((w * 4 + f) * 4 + kc) << 9) + fo];
                acc[0][f] = __builtin_amdgcn_mfma_f32_16x16x32_bf16(af, bx0, acc[0][f], 0, 0, 0);
                acc[1][f] = __builtin_amdgcn_mfma_f32_16x16x32_bf16(af, bx1, acc[1][f], 0, 0, 0);
            }
        }
        if (w < 2) {
            #pragma unroll
            for (int ng = 0; ng < 2; ng++) {
                const int n = n0 + ng * 16 + lm;
                #pragma unroll
                for (int f = 0; f < 4; f++) {
                    const int mb = w * 64 + f * 16 + quad * 4;
                    const int hh = mb >> 5, ddb = mb & 31;
                    uint2 pk;
                    pk.x = cvt_pk(acc[ng][f][0], acc[ng][f][1]);
                    pk.y = cvt_pk(acc[ng][f][2], acc[ng][f][3]);
                    *(uint2*)&Kt[((size_t)(b * NHEADS + hh) * NN + n) * 32 + ddb] = pk;
                }
            }
        } else {
            #pragma unroll
            for (int ng = 0; ng < 2; ng++) {
                const int n = n0 + ng * 16 + lm;
                const size_t nblk = ((size_t)(n >> 5) << 10) + (n & 31);
                #pragma unroll
                for (int f = 0; f < 4; f++) {
                    const int db = (w - 2) * 64 + f * 16 + quad * 4;
                    const int hh = db >> 5;
                    const size_t hb = (size_t)(b * NHEADS + hh) * NN * 32;
                    #pragma unroll
                    for (int r = 0; r < 4; r++) {
                        const int d = (db + r) & 31;
                        unsigned int u = cvt_pk(acc[ng][f][r], 0.f);
                        Vt[hb + nblk + (size_t)d * 32] = (unsigned short)(u & 0xFFFF);
                    }
                }
            }
        }
    }
}

// ---------------- Flash attention: XCD-local groups, 256-n blocks (8 waves) -----------
// REVERTED to the R11-measured version (73.5us, 44 VGPR, FETCH 12.3MB):
// straight in-loop K/V loads, no min-wave bound, no register ping-pong.
// (R12 lesson: __launch_bounds__(512,8) + prefetch regs => scratch spills, 184us.)
__global__ __launch_bounds__(512)
void flash_kernel(const unsigned short* __restrict__ Qt,
                  const unsigned short* __restrict__ Kt,
                  const unsigned short* __restrict__ Vt,
                  unsigned short* __restrict__ Op, float* __restrict__ Lp)
{
    __shared__ unsigned short Ps[8][32][72];

    const int lid = blockIdx.x;
    const int xcd = lid & 7, slot = lid >> 3;       // 128 slots per XCD
    const int g = xcd * 8 + (slot >> 4);            // 64 groups, 8 per XCD
    const int xblk = slot & 15;
    const int half = g >> 4, bh = g & 15;
    const int b = bh >> 2, h = bh & 3;
    const int n0 = xblk * 256;
    const int t = threadIdx.x;
    const int w = t >> 6;                           // 0..7
    const int lm = t & 15, quad = (t & 63) >> 4;

    const unsigned short* Qh = Qt + (size_t)(b * NHEADS + h) * NN * 32;
    const unsigned short* Kh = Kt + (size_t)(b * NHEADS + h) * NN * 32;
    const unsigned short* Vh = Vt + (size_t)(b * NHEADS + h) * NN * 32;

    b8 aq[2];
    aq[0] = *(const b8*)&Qh[(size_t)(n0 + w * 32 + lm) * 32 + quad * 8];
    aq[1] = *(const b8*)&Qh[(size_t)(n0 + w * 32 + 16 + lm) * 32 + quad * 8];

    b8 ones;
    #pragma unroll
    for (int j = 0; j < 8; j++) ones[j] = (__bf16)1.0f;

    f4 ocT[2][2];
    f4 lsum[2];
    #pragma unroll
    for (int u = 0; u < 2; u++) {
        lsum[u] = (f4){0.f, 0.f, 0.f, 0.f};
        ocT[0][u] = (f4){0.f, 0.f, 0.f, 0.f};
        ocT[1][u] = (f4){0.f, 0.f, 0.f, 0.f};
    }

    const int m_lo = half * (NN / SPLITS), m_hi = m_lo + NN / SPLITS;
    for (int m0 = m_lo; m0 < m_hi; m0 += 64) {
        b8 bk[4], av[2][2];
        #pragma unroll
        for (int f = 0; f < 4; f++)
            bk[f] = *(const b8*)&Kh[(size_t)(m0 + f * 16 + lm) * 32 + quad * 8];
        #pragma unroll
        for (int c = 0; c < 2; c++) {
            const size_t vb = (size_t)(m0 + c * 32) * 32 + quad * 8;
            av[0][c] = *(const b8*)&Vh[vb + (size_t)lm * 32];
            av[1][c] = *(const b8*)&Vh[vb + (size_t)(16 + lm) * 32];
        }

        f4 st[4][2];
        #pragma unroll
        for (int f = 0; f < 4; f++)
            #pragma unroll
            for (int u = 0; u < 2; u++) {
                f4 z = {0.f, 0.f, 0.f, 0.f};
                st[f][u] = __builtin_amdgcn_mfma_f32_16x16x32_bf16(bk[f], aq[u], z, 0, 0, 0);
            }

        #pragma unroll
        for (int f = 0; f < 4; f++)
            #pragma unroll
            for (int u = 0; u < 2; u++) {
                uint2 pk;
                pk.x = cvt_pk(fexp2(st[f][u][0]), fexp2(st[f][u][1]));
                pk.y = cvt_pk(fexp2(st[f][u][2]), fexp2(st[f][u][3]));
                *(uint2*)&Ps[w][u * 16 + lm][f * 16 + quad * 4] = pk;
            }

        #pragma unroll
        for (int c = 0; c < 2; c++)
            #pragma unroll
            for (int u = 0; u < 2; u++) {
                b8 bp = *(const b8*)&Ps[w][u * 16 + lm][c * 32 + quad * 8];
                ocT[0][u] = __builtin_amdgcn_mfma_f32_16x16x32_bf16(av[0][c], bp, ocT[0][u], 0, 0, 0);
                ocT[1][u] = __builtin_amdgcn_mfma_f32_16x16x32_bf16(av[1][c], bp, ocT[1][u], 0, 0, 0);
                lsum[u]   = __builtin_amdgcn_mfma_f32_16x16x32_bf16(ones, bp, lsum[u], 0, 0, 0);
            }
    }

    unsigned short* OpB = Op + ((size_t)(half * BB + b) * CLOW + h * HDIM) * NN;
    float* LpB = Lp + ((size_t)(half * BB + b) * NHEADS + h) * NN;
    #pragma unroll
    for (int u = 0; u < 2; u++) {
        const int n = n0 + w * 32 + u * 16 + lm;
        if (quad == 0) LpB[n] = lsum[u][0];
        #pragma unroll
        for (int hh = 0; hh < 2; hh++)
            #pragma unroll
            for (int r = 0; r < 4; r++) {
                const int d = hh * 16 + quad * 4 + r;
                unsigned int uu = cvt_pk(ocT[hh][u][r], 0.f);
                OpB[(size_t)d * NN + n] = (unsigned short)(uu & 0xFFFF);
            }
    }
}

// ---------------- proj: x = low + g*(Wproj @ combine(opart,lpart)); + x stats --------
// grid (N/32, B), block 256 (4 waves; wave -> 32 m rows x both 16n groups).
// Full M=128 per block: combine staging done ONCE (was duplicated across 2 m-blocks).
__global__ __launch_bounds__(256)
void proj_kernel(const unsigned short* __restrict__ Wb,
                 const unsigned short* __restrict__ Opart, const float* __restrict__ Lp,
                 const float* __restrict__ low, float* __restrict__ Xout,
                 const float* __restrict__ gp, float* __restrict__ stOut)
{
    __shared__ unsigned short Xs[32][136];
    __shared__ float red[8];
    const int b = blockIdx.y;
    const int n0 = blockIdx.x * 32;
    const int t = threadIdx.x;
    const int w = t >> 6, lm = t & 15, quad = (t & 63) >> 4;
    const int fo = lm * 32 + quad * 8;
    unsigned int* xw = (unsigned int*)&Xs[0][0];

    #pragma unroll
    for (int it = 0; it < 2; it++) {
        const int s = it * 256 + t;
        const int kp = s >> 3;
        const int k2 = kp << 1;
        const int nc = (s & 7) << 2;
        const size_t ro = (size_t)k2 * NN + n0 + nc;
        const int hh = k2 >> 5;
        const size_t lo = (size_t)(b * NHEADS + hh) * NN + n0 + nc;
        float4 l4 = *(const float4*)&Lp[lo];
        #pragma unroll
        for (int sp = 1; sp < SPLITS; sp++)
            l4 += *(const float4*)&Lp[lo + (size_t)sp * BB * NHEADS * NN];
        float4 pa = {0.f, 0.f, 0.f, 0.f}, pb = {0.f, 0.f, 0.f, 0.f};
        #pragma unroll
        for (int sp = 0; sp < SPLITS; sp++) {
            const unsigned short* Os = Opart + (size_t)sp * BB * CLOW * NN
                                     + (size_t)b * CLOW * NN + ro;
            ushort4 ua = *(const ushort4*)Os;
            ushort4 ub = *(const ushort4*)(Os + NN);
            pa.x += b2f(ua.x); pa.y += b2f(ua.y); pa.z += b2f(ua.z); pa.w += b2f(ua.w);
            pb.x += b2f(ub.x); pb.y += b2f(ub.y); pb.z += b2f(ub.z); pb.w += b2f(ub.w);
        }
        float4 iv;
        iv.x = 1.f / l4.x; iv.y = 1.f / l4.y; iv.z = 1.f / l4.z; iv.w = 1.f / l4.w;
        pa.x *= iv.x; pa.y *= iv.y; pa.z *= iv.z; pa.w *= iv.w;
        pb.x *= iv.x; pb.y *= iv.y; pb.z *= iv.z; pb.w *= iv.w;
        xw[(nc + 0) * 68 + kp] = cvt_pk(pa.x, pb.x);
        xw[(nc + 1) * 68 + kp] = cvt_pk(pa.y, pb.y);
        xw[(nc + 2) * 68 + kp] = cvt_pk(pa.z, pb.z);
        xw[(nc + 3) * 68 + kp] = cvt_pk(pa.w, pb.w);
    }
    __syncthreads();

    f4 acc[2][2];   // [f m-tile][ng n-group]
    #pragma unroll
    for (int f = 0; f < 2; f++) {
        acc[f][0] = (f4){0.f, 0.f, 0.f, 0.f};
        acc[f][1] = (f4){0.f, 0.f, 0.f, 0.f};
    }
    #pragma unroll
    for (int kc = 0; kc < 4; kc++) {
        b8 bx0 = *(const b8*)&Xs[lm][kc * 32 + quad * 8];
        b8 bx1 = *(const b8*)&Xs[16 + lm][kc * 32 + quad * 8];
        #pragma unroll
        for (int f = 0; f < 2; f++) {
            const int mt = w * 2 + f;
            b8 af = *(const b8*)&Wb[((mt * 4 + kc) << 9) + fo];
            acc[f][0] = __builtin_amdgcn_mfma_f32_16x16x32_bf16(af, bx0, acc[f][0], 0, 0, 0);
            acc[f][1] = __builtin_amdgcn_mfma_f32_16x16x32_bf16(af, bx1, acc[f][1], 0, 0, 0);
        }
    }

    const float g = gp[0];
    const float* Rb = low + (size_t)b * CLOW * NN;
    float* Yb = Xout + (size_t)b * CLOW * NN;
    float s = 0.f, s2 = 0.f;
    #pragma unroll
    for (int f = 0; f < 2; f++)
        #pragma unroll
        for (int ng = 0; ng < 2; ng++) {
            const int n = n0 + ng * 16 + lm;
            #pragma unroll
            for (int r = 0; r < 4; r++) {
                const int m = w * 32 + f * 16 + quad * 4 + r;
                const size_t off = (size_t)m * NN + n;
                float v = Rb[off] + g * acc[f][ng][r];
                Yb[off] = v;
                s += v; s2 += v * v;
            }
        }
    for (int off = 32; off; off >>= 1) {
        s  += __shfl_down(s, off, 64);
        s2 += __shfl_down(s2, off, 64);
    }
    if ((t & 63) == 0) { red[w] = s; red[4 + w] = s2; }
    __syncthreads();
    if (t == 0) {
        atomicAdd(&stOut[2 * b], red[0] + red[1] + red[2] + red[3]);
        atomicAdd(&stOut[2 * b + 1], red[4] + red[5] + red[6] + red[7]);
    }
}

// ---------------- fused FFN: out = x + g * (W2 @ gelu(W1 @ norm(x))) ----------------
// grid (N/32, B), block 512 (8 waves). H strip [256][32n] in LDS. Blocked W.
__global__ __launch_bounds__(512)
void ffn_kernel(const unsigned short* __restrict__ W1, const unsigned short* __restrict__ W2,
                const float* __restrict__ X, float* __restrict__ Out,
                const float* __restrict__ nw, const float* __restrict__ nb,
                const float* __restrict__ st, const float* __restrict__ gp)
{
    __shared__ unsigned short Xs[32][136];
    __shared__ unsigned short Hs[32][264];
    const int b = blockIdx.y;
    const int n0 = blockIdx.x * 32;
    const int t = threadIdx.x;
    const int w = t >> 6, lm = t & 15, quad = (t & 63) >> 4;
    const int fo = lm * 32 + quad * 8;

    const float invCnt = 1.0f / ((float)CLOW * NN);
    const float mean = st[2 * b] * invCnt;
    const float rstd = rsqrtf(st[2 * b + 1] * invCnt - mean * mean + EPS);

    const float* Xb = X + (size_t)b * CLOW * NN;
    unsigned int* xw = (unsigned int*)&Xs[0][0];
    {
        const int s = t;
        const int kp = s >> 3;
        const int k2 = kp << 1;
        const int nc = (s & 7) << 2;
        const size_t ro = (size_t)k2 * NN + n0 + nc;
        float4 pa = *(const float4*)&Xb[ro];
        float4 pb = *(const float4*)&Xb[ro + NN];
        const float sc0 = nw[k2] * rstd,     sb0 = nb[k2] - mean * sc0;
        const float sc1 = nw[k2 + 1] * rstd, sb1 = nb[k2 + 1] - mean * sc1;
        pa.x = pa.x * sc0 + sb0; pa.y = pa.y * sc0 + sb0;
        pa.z = pa.z * sc0 + sb0; pa.w = pa.w * sc0 + sb0;
        pb.x = pb.x * sc1 + sb1; pb.y = pb.y * sc1 + sb1;
        pb.z = pb.z * sc1 + sb1; pb.w = pb.w * sc1 + sb1;
        xw[(nc + 0) * 68 + kp] = cvt_pk(pa.x, pb.x);
        xw[(nc + 1) * 68 + kp] = cvt_pk(pa.y, pb.y);
        xw[(nc + 2) * 68 + kp] = cvt_pk(pa.z, pb.z);
        xw[(nc + 3) * 68 + kp] = cvt_pk(pa.w, pb.w);
    }
    __syncthreads();

    // phase1: wave w computes H rows w*32..+32 for both 16n groups
    f4 hv[2][2];
    #pragma unroll
    for (int ng = 0; ng < 2; ng++) {
        hv[ng][0] = (f4){0.f, 0.f, 0.f, 0.f};
        hv[ng][1] = (f4){0.f, 0.f, 0.f, 0.f};
    }
    #pragma unroll
    for (int kc = 0; kc < 4; kc++) {
        b8 bx0 = *(const b8*)&Xs[lm][kc * 32 + quad * 8];
        b8 bx1 = *(const b8*)&Xs[16 + lm][kc * 32 + quad * 8];
        #pragma unroll
        for (int f = 0; f < 2; f++) {
            const int mt = w * 2 + f;
            b8 af = *(const b8*)&W1[((mt * 4 + kc) << 9) + fo];
            hv[0][f] = __builtin_amdgcn_mfma_f32_16x16x32_bf16(af, bx0, hv[0][f], 0, 0, 0);
            hv[1][f] = __builtin_amdgcn_mfma_f32_16x16x32_bf16(af, bx1, hv[1][f], 0, 0, 0);
        }
    }
    #pragma unroll
    for (int ng = 0; ng < 2; ng++)
        #pragma unroll
        for (int f = 0; f < 2; f++) {
            float g0 = hv[ng][f][0], g1 = hv[ng][f][1];
            float g2 = hv[ng][f][2], g3 = hv[ng][f][3];
            g0 = 0.5f * g0 * (1.f + erff(g0 * 0.70710678118654752f));
            g1 = 0.5f * g1 * (1.f + erff(g1 * 0.70710678118654752f));
            g2 = 0.5f * g2 * (1.f + erff(g2 * 0.70710678118654752f));
            g3 = 0.5f * g3 * (1.f + erff(g3 * 0.70710678118654752f));
            uint2 pk;
            pk.x = cvt_pk(g0, g1);
            pk.y = cvt_pk(g2, g3);
            *(uint2*)&Hs[ng * 16 + lm][w * 32 + f * 16 + quad * 4] = pk;
        }
    __syncthreads();

    // phase2: wave w computes out rows w*16..+16 for both 16n groups
    f4 o[2];
    o[0] = (f4){0.f, 0.f, 0.f, 0.f};
    o[1] = (f4){0.f, 0.f, 0.f, 0.f};
    #pragma unroll
    for (int kc = 0; kc < 8; kc++) {
        b8 bh0 = *(const b8*)&Hs[lm][kc * 32 + quad * 8];
        b8 bh1 = *(const b8*)&Hs[16 + lm][kc * 32 + quad * 8];
        b8 af = *(const b8*)&W2[((w * 8 + kc) << 9) + fo];
        o[0] = __builtin_amdgcn_mfma_f32_16x16x32_bf16(af, bh0, o[0], 0, 0, 0);
        o[1] = __builtin_amdgcn_mfma_f32_16x16x32_bf16(af, bh1, o[1], 0, 0, 0);
    }
    const float g = gp[0];
    float* Ob = Out + (size_t)b * CLOW * NN;
    #pragma unroll
    for (int ng = 0; ng < 2; ng++) {
        const int n = n0 + ng * 16 + lm;
        #pragma unroll
        for (int r = 0; r < 4; r++) {
            const int m = w * 16 + quad * 4 + r;
            const size_t off = (size_t)m * NN + n;
            Ob[off] = Xb[off] + g * o[ng][r];
        }
    }
}

extern "C" void kernel_launch(void* const* d_in, const int* in_sizes, int n_in,
                              void* d_out, int out_size, void* d_ws, size_t ws_size,
                              hipStream_t stream)
{
    const float* high  = (const float*)d_in[0];
    const float* low   = (const float*)d_in[1];
    const float* nh_w  = (const float*)d_in[2];
    const float* nh_b  = (const float*)d_in[3];
    const float* nl_w  = (const float*)d_in[4];
    const float* nl_b  = (const float*)d_in[5];
    const float* nf_w  = (const float*)d_in[6];
    const float* nf_b  = (const float*)d_in[7];
    const float* Wq    = (const float*)d_in[8];
    const float* Wk    = (const float*)d_in[9];
    const float* Wv    = (const float*)d_in[10];
    const float* Wproj = (const float*)d_in[11];
    const float* Wff1  = (const float*)d_in[12];
    const float* Wff2  = (const float*)d_in[13];
    const float* g_at  = (const float*)d_in[14];
    const float* g_ff  = (const float*)d_in[15];
    float* out = (float*)d_out;

    float* ws    = (float*)d_ws;
    float* stats = ws;                                       // 64 floats
    unsigned short* wbf = (unsigned short*)(ws + 64);        // 147456 bf16 weights (blocked)
    unsigned short* qt = wbf + 147456;                       // [B][NH][NN][32] bf16
    unsigned short* kt = qt + (size_t)BB * NHEADS * NN * 32;
    unsigned short* vt = kt + (size_t)BB * NHEADS * NN * 32; // blocked bf16
    unsigned short* opart = vt + (size_t)BB * CLOW * NN;     // [SPLITS][B][CLOW][NN] bf16
    float* lpart = (float*)(opart + (size_t)SPLITS * BB * CLOW * NN);
    float* x     = lpart + (size_t)SPLITS * BB * NHEADS * NN;

    (void)hipMemsetAsync(stats, 0, 64 * sizeof(float), stream);

    prep_kernel<<<dim3(64, BB, 3), 256, 0, stream>>>(high, low, stats,
                                                     Wq, Wk, Wv, Wproj, Wff1, Wff2, wbf);

    qkv_kernel<<<dim3(128, BB, 2), 256, 0, stream>>>(wbf, high, low, qt, kt, vt,
                                                     nh_w, nh_b, nl_w, nl_b, stats);

    flash_kernel<<<dim3(1024), 512, 0, stream>>>(qt, kt, vt, opart, lpart);

    proj_kernel<<<dim3(128, BB), 256, 0, stream>>>(wbf + 65536, opart, lpart,
                                                   low, x, g_at, stats + 16);

    ffn_kernel<<<dim3(128, BB), 512, 0, stream>>>(wbf + 81920, wbf + 114688, x, out,
                                                  nf_w, nf_b, stats + 16, g_ff);
}